// Round 2
// baseline (1197.999 us; speedup 1.0000x reference)
//
#include <hip/hip_runtime.h>

// Problem constants (from reference setup_inputs)
#define B_   64
#define E_   100000
#define C_   80000
#define N_   10000
#define NNZ_ 1600000
#define GS   8        // channels per group = C/N (channel_groups = arange(C)//8)
#define EPS_ 1e-5f

// ---------------------------------------------------------------------------
// Transpose x [B=64, E] -> xT [E, 64] via 64x64 LDS tile (pad +1 col).
// ---------------------------------------------------------------------------
__global__ void transpose_x_kernel(const float* __restrict__ x, float* __restrict__ xT) {
    __shared__ float tile[64][65];
    const int e0 = blockIdx.x * 64;
    const int t  = threadIdx.x;      // 256 threads
    const int c  = t & 63;
    const int r4 = t >> 6;
#pragma unroll
    for (int j = 0; j < 16; ++j) {
        int br = r4 * 16 + j;        // batch row 0..63
        int e  = e0 + c;
        if (e < E_) tile[c][br] = x[br * E_ + e];
    }
    __syncthreads();
#pragma unroll
    for (int j = 0; j < 16; ++j) {
        int er = r4 * 16 + j;
        int e  = e0 + er;
        if (e < E_) xT[e * 64 + c] = tile[er][c];
    }
}

// ---------------------------------------------------------------------------
// CSR build step 1: histogram of column indices. counts must be pre-zeroed.
// ---------------------------------------------------------------------------
__global__ void hist_kernel(const int* __restrict__ cols, int* __restrict__ counts, int nnz) {
    const int tid    = blockIdx.x * blockDim.x + threadIdx.x;
    const int stride = gridDim.x * blockDim.x;
    for (int k = tid; k < nnz; k += stride) atomicAdd(&counts[cols[k]], 1);
}

// ---------------------------------------------------------------------------
// CSR build step 2: exclusive scan of counts[0..dim) -> offsets[0..dim] and
// cursor[0..dim). Single block, 1024 threads, chunked + Hillis-Steele.
// ---------------------------------------------------------------------------
__global__ __launch_bounds__(1024) void scan_kernel(const int* __restrict__ counts,
                                                    int* __restrict__ offsets,
                                                    int* __restrict__ cursor, int dim) {
    __shared__ int part[1024];
    const int t  = threadIdx.x;
    const int CH = (dim + 1023) / 1024;
    const int lo = t * CH;
    const int hi = min(dim, lo + CH);
    int s = 0;
    for (int i = lo; i < hi; ++i) s += counts[i];
    part[t] = s;
    __syncthreads();
    // inclusive Hillis-Steele scan over 1024 partials
    for (int d = 1; d < 1024; d <<= 1) {
        int v = (t >= d) ? part[t - d] : 0;
        __syncthreads();
        part[t] += v;
        __syncthreads();
    }
    int run = (t == 0) ? 0 : part[t - 1];
    for (int i = lo; i < hi; ++i) {
        offsets[i] = run;
        cursor[i]  = run;
        run += counts[i];
    }
    if (hi == dim) offsets[dim] = run;   // total (threads past end also write total)
}

// ---------------------------------------------------------------------------
// CSR build step 3: fill packed {row, val} pairs grouped by column.
// ---------------------------------------------------------------------------
__global__ void fill_kernel(const int* __restrict__ rows, const int* __restrict__ cols,
                            const float* __restrict__ vals, int* __restrict__ cursor,
                            float2* __restrict__ csr, int nnz) {
    const int tid    = blockIdx.x * blockDim.x + threadIdx.x;
    const int stride = gridDim.x * blockDim.x;
    for (int k = tid; k < nnz; k += stride) {
        const int c   = cols[k];
        const int pos = atomicAdd(&cursor[c], 1);
        csr[pos] = make_float2(__int_as_float(rows[k]), vals[k]);
    }
}

// ---------------------------------------------------------------------------
// Phase 1: gather h[c][b] = b_in[c] + sum csr, then fused GroupLayerNorm+ELU.
// One wave per group of 8 channels; lane = batch; everything in registers.
// ---------------------------------------------------------------------------
__global__ void gather_gln_kernel(const float2* __restrict__ csr, const int* __restrict__ offsets,
                                  const float* __restrict__ xT, const float* __restrict__ b_in,
                                  const float* __restrict__ gamma, const float* __restrict__ beta,
                                  float* __restrict__ h) {
    const int wave = blockIdx.x * (blockDim.x >> 6) + (threadIdx.x >> 6);
    const int lane = threadIdx.x & 63;
    if (wave >= N_) return;
    const int c0 = wave * GS;
    float acc[GS];
    float s = 0.f, s2 = 0.f;
#pragma unroll
    for (int j = 0; j < GS; ++j) {
        const int c   = c0 + j;
        const int beg = offsets[c];
        const int end = offsets[c + 1];
        float a = b_in[c];
        for (int i = beg; i < end; ++i) {
            float2 p = csr[i];                       // wave-uniform 8B broadcast
            a = fmaf(p.y, xT[__float_as_int(p.x) * 64 + lane], a);
        }
        acc[j] = a;
        s  += a;
        s2 += a * a;
    }
    const float mean = s * (1.0f / GS);
    const float var  = s2 * (1.0f / GS) - mean * mean;
    const float inv  = rsqrtf(var + EPS_);
#pragma unroll
    for (int j = 0; j < GS; ++j) {
        const float hn = (acc[j] - mean) * inv;
        const float g  = gamma[c0 + j] * hn + beta[c0 + j];
        h[(c0 + j) * 64 + lane] = (g > 0.f) ? g : expm1f(g);   // ELU alpha=1
    }
}

// ---------------------------------------------------------------------------
// Phase 2: gather out edges + fused b_out + residual + transpose to [B, E].
// Block handles 64 consecutive e; 4 waves x 16 columns each; LDS transpose.
// ---------------------------------------------------------------------------
__global__ void gather_out_kernel(const float2* __restrict__ csr, const int* __restrict__ offsets,
                                  const float* __restrict__ h, const float* __restrict__ b_out,
                                  const float* __restrict__ x, float* __restrict__ out) {
    __shared__ float tile[64][65];
    const int e0   = blockIdx.x * 64;
    const int lane = threadIdx.x & 63;
    const int w    = threadIdx.x >> 6;     // 0..3
#pragma unroll
    for (int j = 0; j < 16; ++j) {
        const int el = w * 16 + j;
        const int e  = e0 + el;
        float a = 0.f;
        if (e < E_) {
            const int beg = offsets[e];
            const int end = offsets[e + 1];
            for (int i = beg; i < end; ++i) {
                float2 p = csr[i];
                a = fmaf(p.y, h[__float_as_int(p.x) * 64 + lane], a);
            }
        }
        tile[el][lane] = a;
    }
    __syncthreads();
#pragma unroll
    for (int j = 0; j < 16; ++j) {
        const int br = w * 16 + j;
        const int e  = e0 + lane;
        if (e < E_) out[br * E_ + e] = tile[lane][br] + b_out[e] + x[br * E_ + e];
    }
}

// ---------------------------------------------------------------------------
extern "C" void kernel_launch(void* const* d_in, const int* in_sizes, int n_in,
                              void* d_out, int out_size, void* d_ws, size_t ws_size,
                              hipStream_t stream) {
    const float* x     = (const float*)d_in[0];
    const float* v_in  = (const float*)d_in[1];
    const float* b_in  = (const float*)d_in[2];
    const float* v_out = (const float*)d_in[3];
    const float* b_out = (const float*)d_in[4];
    const float* gamma = (const float*)d_in[5];
    const float* beta  = (const float*)d_in[6];
    const int* w_in_rows  = (const int*)d_in[7];
    const int* w_in_cols  = (const int*)d_in[8];
    const int* w_out_rows = (const int*)d_in[9];
    const int* w_out_cols = (const int*)d_in[10];
    // d_in[11] = channel_groups: provably arange(C)//8 (consecutive groups of 8)
    float* out = (float*)d_out;

    // Workspace layout (floats):
    //   xT      E_*64   = 6,400,000
    //   h       C_*64   = 5,120,000
    //   counts  100,000 ints (max(E_, C_))
    //   offsets 100,001 ints
    //   cursor  100,000 ints  (+1 pad for 8B alignment of csr)
    //   csr     NNZ_ float2 = 12.8 MB
    // total ~60.1 MB
    float* xT      = (float*)d_ws;
    float* h       = xT + E_ * 64;
    int*   counts  = (int*)(h + C_ * 64);
    int*   offsets = counts + 100000;
    int*   cursor  = offsets + 100001;
    float2* csr    = (float2*)(cursor + 100000 + 1);   // 8B-aligned

    transpose_x_kernel<<<(E_ + 63) / 64, 256, 0, stream>>>(x, xT);

    // --- phase 1: input sparse linear (by hidden channel) + GLN + ELU ---
    hipMemsetAsync(counts, 0, C_ * sizeof(int), stream);
    hist_kernel<<<2048, 256, 0, stream>>>(w_in_cols, counts, NNZ_);
    scan_kernel<<<1, 1024, 0, stream>>>(counts, offsets, cursor, C_);
    fill_kernel<<<2048, 256, 0, stream>>>(w_in_rows, w_in_cols, v_in, cursor, csr, NNZ_);
    gather_gln_kernel<<<(N_ + 3) / 4, 256, 0, stream>>>(csr, offsets, xT, b_in, gamma, beta, h);

    // --- phase 2: output sparse linear (by edge) + bias + residual ---
    hipMemsetAsync(counts, 0, E_ * sizeof(int), stream);
    hist_kernel<<<2048, 256, 0, stream>>>(w_out_cols, counts, NNZ_);
    scan_kernel<<<1, 1024, 0, stream>>>(counts, offsets, cursor, E_);
    fill_kernel<<<2048, 256, 0, stream>>>(w_out_rows, w_out_cols, v_out, cursor, csr, NNZ_);
    gather_out_kernel<<<(E_ + 63) / 64, 256, 0, stream>>>(csr, offsets, h, b_out, x, out);
}

// Round 3
// 653.931 us; speedup vs baseline: 1.8320x; 1.8320x over previous
//
#include <hip/hip_runtime.h>

// Problem constants (from reference setup_inputs)
#define B_   64
#define E_   100000
#define C_   80000
#define N_   10000
#define NNZ_ 1600000
#define GS   8        // channels per group = C/N (channel_groups = arange(C)//8)
#define EPS_ 1e-5f

#define SCAN_CHUNK 1024   // elements per block in the scan (256 thr x 4)

// ---------------------------------------------------------------------------
// Transpose x [B=64, E] -> xT [E, 64] via 64x64 LDS tile (pad +1 col).
// ---------------------------------------------------------------------------
__global__ void transpose_x_kernel(const float* __restrict__ x, float* __restrict__ xT) {
    __shared__ float tile[64][65];
    const int e0 = blockIdx.x * 64;
    const int t  = threadIdx.x;      // 256 threads
    const int c  = t & 63;
    const int r4 = t >> 6;
#pragma unroll
    for (int j = 0; j < 16; ++j) {
        int br = r4 * 16 + j;        // batch row 0..63
        int e  = e0 + c;
        if (e < E_) tile[c][br] = x[br * E_ + e];
    }
    __syncthreads();
#pragma unroll
    for (int j = 0; j < 16; ++j) {
        int er = r4 * 16 + j;
        int e  = e0 + er;
        if (e < E_) xT[e * 64 + c] = tile[er][c];
    }
}

// ---------------------------------------------------------------------------
// CSR build step 1: histogram of column indices. counts must be pre-zeroed.
// ---------------------------------------------------------------------------
__global__ void hist_kernel(const int* __restrict__ cols, int* __restrict__ counts, int nnz) {
    const int tid    = blockIdx.x * blockDim.x + threadIdx.x;
    const int stride = gridDim.x * blockDim.x;
    for (int k = tid; k < nnz; k += stride) atomicAdd(&counts[cols[k]], 1);
}

// ---------------------------------------------------------------------------
// CSR build step 2a: per-block chunk sums (1024 counts per block).
// ---------------------------------------------------------------------------
__global__ void scan_partial_kernel(const int* __restrict__ counts, int* __restrict__ partials,
                                    int dim) {
    __shared__ int red[256];
    const int t    = threadIdx.x;
    const int base = blockIdx.x * SCAN_CHUNK + t * 4;
    int s = 0;
#pragma unroll
    for (int j = 0; j < 4; ++j) { int i = base + j; if (i < dim) s += counts[i]; }
    red[t] = s;
    __syncthreads();
    for (int d = 128; d > 0; d >>= 1) {
        if (t < d) red[t] += red[t + d];
        __syncthreads();
    }
    if (t == 0) partials[blockIdx.x] = red[0];
}

// ---------------------------------------------------------------------------
// CSR build step 2b: exclusive scan of <=256 partials, single small block.
// ---------------------------------------------------------------------------
__global__ void scan_base_kernel(int* __restrict__ partials, int nparts) {
    __shared__ int buf[256];
    const int t = threadIdx.x;
    buf[t] = (t < nparts) ? partials[t] : 0;
    __syncthreads();
    for (int d = 1; d < 256; d <<= 1) {
        int v = (t >= d) ? buf[t - d] : 0;
        __syncthreads();
        buf[t] += v;
        __syncthreads();
    }
    if (t < nparts) partials[t] = (t == 0) ? 0 : buf[t - 1];
}

// ---------------------------------------------------------------------------
// CSR build step 2c: emit offsets + cursor for each chunk using its base.
// ---------------------------------------------------------------------------
__global__ void scan_emit_kernel(const int* __restrict__ counts, const int* __restrict__ partials,
                                 int* __restrict__ offsets, int* __restrict__ cursor, int dim) {
    __shared__ int red[256];
    const int t    = threadIdx.x;
    const int base = blockIdx.x * SCAN_CHUNK + t * 4;
    int v[4];
    int s = 0;
#pragma unroll
    for (int j = 0; j < 4; ++j) {
        int i = base + j;
        v[j] = (i < dim) ? counts[i] : 0;
        s += v[j];
    }
    red[t] = s;
    __syncthreads();
    for (int d = 1; d < 256; d <<= 1) {
        int u = (t >= d) ? red[t - d] : 0;
        __syncthreads();
        red[t] += u;
        __syncthreads();
    }
    int run = partials[blockIdx.x] + ((t == 0) ? 0 : red[t - 1]);
#pragma unroll
    for (int j = 0; j < 4; ++j) {
        int i = base + j;
        if (i < dim) { offsets[i] = run; cursor[i] = run; }
        run += v[j];
    }
    if (blockIdx.x == 0 && t == 0) offsets[dim] = NNZ_;   // total is always NNZ
}

// ---------------------------------------------------------------------------
// CSR build step 3: fill packed {row, val} pairs grouped by column.
// ---------------------------------------------------------------------------
__global__ void fill_kernel(const int* __restrict__ rows, const int* __restrict__ cols,
                            const float* __restrict__ vals, int* __restrict__ cursor,
                            float2* __restrict__ csr, int nnz) {
    const int tid    = blockIdx.x * blockDim.x + threadIdx.x;
    const int stride = gridDim.x * blockDim.x;
    for (int k = tid; k < nnz; k += stride) {
        const int c   = cols[k];
        const int pos = atomicAdd(&cursor[c], 1);
        csr[pos] = make_float2(__int_as_float(rows[k]), vals[k]);
    }
}

// ---------------------------------------------------------------------------
// Gather SpMM: one wave per destination, 4x unrolled (4 chains in flight).
// dst[d][lane] = bias(opt) + sum_i csr{row,val} * src[row][lane]
// ---------------------------------------------------------------------------
__global__ void gather_kernel(const float2* __restrict__ csr, const int* __restrict__ offsets,
                              const float* __restrict__ src, const float* __restrict__ bias,
                              float* __restrict__ dst, int dim) {
    const int wave = (blockIdx.x * blockDim.x + threadIdx.x) >> 6;
    const int lane = threadIdx.x & 63;
    if (wave >= dim) return;
    const int beg = offsets[wave];
    const int end = offsets[wave + 1];
    float a0 = bias ? bias[wave] : 0.f, a1 = 0.f, a2 = 0.f, a3 = 0.f;
    int i = beg;
    for (; i + 4 <= end; i += 4) {
        float2 p0 = csr[i], p1 = csr[i + 1], p2 = csr[i + 2], p3 = csr[i + 3];
        a0 = fmaf(p0.y, src[__float_as_int(p0.x) * 64 + lane], a0);
        a1 = fmaf(p1.y, src[__float_as_int(p1.x) * 64 + lane], a1);
        a2 = fmaf(p2.y, src[__float_as_int(p2.x) * 64 + lane], a2);
        a3 = fmaf(p3.y, src[__float_as_int(p3.x) * 64 + lane], a3);
    }
    for (; i < end; ++i) {
        float2 p = csr[i];
        a0 = fmaf(p.y, src[__float_as_int(p.x) * 64 + lane], a0);
    }
    dst[wave * 64 + lane] = (a0 + a1) + (a2 + a3);
}

// ---------------------------------------------------------------------------
// GroupLayerNorm + ELU, in place on h [C, 64] (b_in already added by gather).
// One wave per group of 8 consecutive channels; lane = batch; stats in regs.
// ---------------------------------------------------------------------------
__global__ void gln_elu_kernel(float* __restrict__ h,
                               const float* __restrict__ gamma, const float* __restrict__ beta) {
    const int wave = blockIdx.x * (blockDim.x >> 6) + (threadIdx.x >> 6);
    const int b    = threadIdx.x & 63;
    if (wave >= N_) return;
    const int c0 = wave * GS;
    float v[GS];
    float s = 0.f, s2 = 0.f;
#pragma unroll
    for (int j = 0; j < GS; ++j) {
        float t = h[(c0 + j) * 64 + b];
        v[j] = t;
        s  += t;
        s2 += t * t;
    }
    const float mean = s * (1.0f / GS);
    const float var  = s2 * (1.0f / GS) - mean * mean;
    const float inv  = rsqrtf(var + EPS_);
#pragma unroll
    for (int j = 0; j < GS; ++j) {
        float hn = (v[j] - mean) * inv;
        float g  = gamma[c0 + j] * hn + beta[c0 + j];
        h[(c0 + j) * 64 + b] = (g > 0.f) ? g : expm1f(g);  // ELU alpha=1
    }
}

// ---------------------------------------------------------------------------
// Finalize: out [64, E] = transpose(outT [E,64]) + b_out[e] + x[b][e]
// ---------------------------------------------------------------------------
__global__ void finalize_kernel(const float* __restrict__ outT, const float* __restrict__ x,
                                const float* __restrict__ b_out, float* __restrict__ out) {
    __shared__ float tile[64][65];
    const int e0 = blockIdx.x * 64;
    const int t  = threadIdx.x;
    const int c  = t & 63;
    const int r4 = t >> 6;
#pragma unroll
    for (int j = 0; j < 16; ++j) {
        int er = r4 * 16 + j;
        int e  = e0 + er;
        if (e < E_) tile[er][c] = outT[e * 64 + c];
    }
    __syncthreads();
#pragma unroll
    for (int j = 0; j < 16; ++j) {
        int br = r4 * 16 + j;
        int e  = e0 + c;
        if (e < E_) out[br * E_ + e] = tile[c][br] + b_out[e] + x[br * E_ + e];
    }
}

// ---------------------------------------------------------------------------
extern "C" void kernel_launch(void* const* d_in, const int* in_sizes, int n_in,
                              void* d_out, int out_size, void* d_ws, size_t ws_size,
                              hipStream_t stream) {
    const float* x     = (const float*)d_in[0];
    const float* v_in  = (const float*)d_in[1];
    const float* b_in  = (const float*)d_in[2];
    const float* v_out = (const float*)d_in[3];
    const float* b_out = (const float*)d_in[4];
    const float* gamma = (const float*)d_in[5];
    const float* beta  = (const float*)d_in[6];
    const int* w_in_rows  = (const int*)d_in[7];
    const int* w_in_cols  = (const int*)d_in[8];
    const int* w_out_rows = (const int*)d_in[9];
    const int* w_out_cols = (const int*)d_in[10];
    // d_in[11] = channel_groups: provably arange(C)//8 (consecutive groups of 8)
    float* out = (float*)d_out;

    // Workspace layout (4-byte units):
    //   bufT    E_*64  floats (xT for phase 1, reused as outT for phase 2)
    //   h       C_*64  floats
    //   counts  100,000 ints
    //   offsets 100,001 ints
    //   cursor  100,000 ints
    //   partials 256 ints (+pad to keep csr 8B-aligned)
    //   csr     NNZ_ float2
    float*  bufT     = (float*)d_ws;
    float*  h        = bufT + E_ * 64;
    int*    counts   = (int*)(h + C_ * 64);
    int*    offsets  = counts + 100000;
    int*    cursor   = offsets + 100001;
    int*    partials = cursor + 100000;
    float2* csr      = (float2*)(partials + 256 + 1);   // 8B-aligned (offset even)

    const int nparts_C = (C_ + SCAN_CHUNK - 1) / SCAN_CHUNK;   // 79
    const int nparts_E = (E_ + SCAN_CHUNK - 1) / SCAN_CHUNK;   // 98

    transpose_x_kernel<<<(E_ + 63) / 64, 256, 0, stream>>>(x, bufT);

    // --- phase 1: input sparse linear (grouped by hidden channel) ---
    hipMemsetAsync(counts, 0, C_ * sizeof(int), stream);
    hist_kernel<<<2048, 256, 0, stream>>>(w_in_cols, counts, NNZ_);
    scan_partial_kernel<<<nparts_C, 256, 0, stream>>>(counts, partials, C_);
    scan_base_kernel<<<1, 256, 0, stream>>>(partials, nparts_C);
    scan_emit_kernel<<<nparts_C, 256, 0, stream>>>(counts, partials, offsets, cursor, C_);
    fill_kernel<<<2048, 256, 0, stream>>>(w_in_rows, w_in_cols, v_in, cursor, csr, NNZ_);
    gather_kernel<<<(C_ + 3) / 4, 256, 0, stream>>>(csr, offsets, bufT, b_in, h, C_);
    gln_elu_kernel<<<(N_ + 3) / 4, 256, 0, stream>>>(h, gamma, beta);

    // --- phase 2: output sparse linear (grouped by edge) ---
    hipMemsetAsync(counts, 0, E_ * sizeof(int), stream);
    hist_kernel<<<2048, 256, 0, stream>>>(w_out_cols, counts, NNZ_);
    scan_partial_kernel<<<nparts_E, 256, 0, stream>>>(counts, partials, E_);
    scan_base_kernel<<<1, 256, 0, stream>>>(partials, nparts_E);
    scan_emit_kernel<<<nparts_E, 256, 0, stream>>>(counts, partials, offsets, cursor, E_);
    fill_kernel<<<2048, 256, 0, stream>>>(w_out_rows, w_out_cols, v_out, cursor, csr, NNZ_);
    gather_kernel<<<(E_ + 3) / 4, 256, 0, stream>>>(csr, offsets, h, nullptr, bufT, E_);

    finalize_kernel<<<(E_ + 63) / 64, 256, 0, stream>>>(bufT, x, b_out, out);
}